// Round 5
// baseline (56.030 us; speedup 1.0000x reference)
//
#include <hip/hip_runtime.h>

#define ROWS   1024
#define COLS   32768
#define BLOCK  256
#define NWAVE  (BLOCK / 64)      // 4 waves per block
#define VEC    8                 // elements per thread per tile
#define TILE   (BLOCK * VEC)     // 2048 elements per tile
#define NTILES (COLS / TILE)     // 16 tiles per row

// Native clang vector type: __builtin_nontemporal_store requires a vector of
// scalars, not HIP's HIP_vector_type struct.
typedef float vfloat4 __attribute__((ext_vector_type(4)));

__device__ __forceinline__ void load_tile(const float* __restrict__ p,
                                          vfloat4& a, vfloat4& b) {
    a = *reinterpret_cast<const vfloat4*>(p);
    b = *reinterpret_cast<const vfloat4*>(p + 4);
}

__global__ __launch_bounds__(BLOCK) void cumprod_nt_kernel(
    const float* __restrict__ x, float* __restrict__ out) {
    // Double-buffered wave totals: one raw barrier per round, no vmcnt drain.
    __shared__ float s_wave[2][NWAVE];

    const int row  = blockIdx.x;
    const int tid  = threadIdx.x;
    const int lane = tid & 63;
    const int wave = tid >> 6;

    const float* __restrict__ xrow = x   + (size_t)row * COLS;
    float* __restrict__       orow = out + (size_t)row * COLS;
    const float* __restrict__ base = xrow + tid * VEC;

    float carry = 1.0f;

    // Prologue: tiles 0 and 1 in flight / in regs.
    vfloat4 a0, b0, a1, b1;
    load_tile(base + 0 * TILE, a0, b0);
    load_tile(base + 1 * TILE, a1, b1);

    for (int t = 0; t < NTILES; ++t) {
        // Prefetch tile t+2 — stays in flight across the raw barrier.
        vfloat4 an, bn;
        const int tp = (t + 2 < NTILES) ? (t + 2) : t;  // clamped tail reload (L1-hot)
        load_tile(base + tp * TILE, an, bn);

        // Local inclusive product chain over this thread's 8 elements.
        float p0 = a0.x;
        float p1 = p0 * a0.y;
        float p2 = p1 * a0.z;
        float p3 = p2 * a0.w;
        float p4 = p3 * b0.x;
        float p5 = p4 * b0.y;
        float p6 = p5 * b0.z;
        float p7 = p6 * b0.w;

        // Wave-level inclusive scan (product) of per-thread totals.
        float incl = p7;
        #pragma unroll
        for (int d = 1; d < 64; d <<= 1) {
            float o = __shfl_up(incl, d, 64);
            if (lane >= d) incl *= o;
        }
        float excl = __shfl_up(incl, 1, 64);
        if (lane == 0) excl = 1.0f;

        // Cross-wave combine through LDS. LDS-only ordering: lgkmcnt(0) +
        // raw s_barrier — global prefetch loads are NOT drained.
        const int buf = t & 1;
        if (lane == 63) s_wave[buf][wave] = incl;
        asm volatile("s_waitcnt lgkmcnt(0)" ::: "memory");
        __builtin_amdgcn_s_barrier();
        asm volatile("" ::: "memory");

        float wpre = 1.0f;   // product of earlier waves' totals (this tile)
        float btot = 1.0f;   // whole-tile product
        #pragma unroll
        for (int w = 0; w < NWAVE; ++w) {
            float v = s_wave[buf][w];   // broadcast read
            wpre *= (w < wave) ? v : 1.0f;
            btot *= v;
        }

        const float pref = carry * wpre * excl;

        vfloat4 o0, o1;
        o0.x = pref * p0; o0.y = pref * p1; o0.z = pref * p2; o0.w = pref * p3;
        o1.x = pref * p4; o1.y = pref * p5; o1.z = pref * p6; o1.w = pref * p7;
        float* __restrict__ dstp = orow + t * TILE + tid * VEC;
        // Non-temporal: output is never re-read -> don't let it evict the
        // (L3-resident) input stream across replays.
        __builtin_nontemporal_store(o0, reinterpret_cast<vfloat4*>(dstp));
        __builtin_nontemporal_store(o1, reinterpret_cast<vfloat4*>(dstp + 4));

        carry *= btot;

        // Rotate the prefetch pipeline.
        a0 = a1; b0 = b1;
        a1 = an; b1 = bn;
    }
}

extern "C" void kernel_launch(void* const* d_in, const int* in_sizes, int n_in,
                              void* d_out, int out_size, void* d_ws, size_t ws_size,
                              hipStream_t stream) {
    const float* x = (const float*)d_in[0];
    float* out     = (float*)d_out;
    cumprod_nt_kernel<<<dim3(ROWS), dim3(BLOCK), 0, stream>>>(x, out);
}

// Round 6
// 39.018 us; speedup vs baseline: 1.4360x; 1.4360x over previous
//
#include <hip/hip_runtime.h>

#define ROWS   1024
#define COLS   32768
#define BLOCK  512
#define NWAVE  (BLOCK / 64)      // 8 waves per block
#define VEC    8                 // elements per thread per tile
#define TILE   (BLOCK * VEC)     // 4096 elements per tile
#define NTILES (COLS / TILE)     // 8 tiles per row

typedef float vfloat4 __attribute__((ext_vector_type(4)));

__device__ __forceinline__ void load_tile(const float* __restrict__ p,
                                          vfloat4& a, vfloat4& b) {
    a = *reinterpret_cast<const vfloat4*>(p);
    b = *reinterpret_cast<const vfloat4*>(p + 4);
}

__global__ __launch_bounds__(BLOCK) void cumprod_w512_kernel(
    const float* __restrict__ x, float* __restrict__ out) {
    // Double-buffered wave totals: one raw barrier per round, no vmcnt drain.
    __shared__ float s_wave[2][NWAVE];

    const int row  = blockIdx.x;
    const int tid  = threadIdx.x;
    const int lane = tid & 63;
    const int wave = tid >> 6;

    const float* __restrict__ xrow = x   + (size_t)row * COLS;
    float* __restrict__       orow = out + (size_t)row * COLS;
    const float* __restrict__ base = xrow + tid * VEC;

    float carry = 1.0f;

    // Prologue: tiles 0 and 1 in flight / in regs.
    vfloat4 a0, b0, a1, b1;
    load_tile(base + 0 * TILE, a0, b0);
    load_tile(base + 1 * TILE, a1, b1);

    for (int t = 0; t < NTILES; ++t) {
        // Prefetch tile t+2 — stays in flight across the raw barrier.
        vfloat4 an, bn;
        const int tp = (t + 2 < NTILES) ? (t + 2) : t;  // clamped tail reload (cache-hot)
        load_tile(base + tp * TILE, an, bn);

        // Local inclusive product chain over this thread's 8 elements.
        float p0 = a0.x;
        float p1 = p0 * a0.y;
        float p2 = p1 * a0.z;
        float p3 = p2 * a0.w;
        float p4 = p3 * b0.x;
        float p5 = p4 * b0.y;
        float p6 = p5 * b0.z;
        float p7 = p6 * b0.w;

        // Wave-level inclusive scan (product) of per-thread totals.
        float incl = p7;
        #pragma unroll
        for (int d = 1; d < 64; d <<= 1) {
            float o = __shfl_up(incl, d, 64);
            if (lane >= d) incl *= o;
        }
        float excl = __shfl_up(incl, 1, 64);
        if (lane == 0) excl = 1.0f;

        // Cross-wave combine through LDS. LDS-only ordering: lgkmcnt(0) +
        // raw s_barrier — global prefetch loads are NOT drained.
        const int buf = t & 1;
        if (lane == 63) s_wave[buf][wave] = incl;
        asm volatile("s_waitcnt lgkmcnt(0)" ::: "memory");
        __builtin_amdgcn_s_barrier();
        asm volatile("" ::: "memory");

        float wpre = 1.0f;   // product of earlier waves' totals (this tile)
        float btot = 1.0f;   // whole-tile product
        #pragma unroll
        for (int w = 0; w < NWAVE; ++w) {
            float v = s_wave[buf][w];   // broadcast read
            wpre *= (w < wave) ? v : 1.0f;
            btot *= v;
        }

        const float pref = carry * wpre * excl;

        vfloat4 o0, o1;
        o0.x = pref * p0; o0.y = pref * p1; o0.z = pref * p2; o0.w = pref * p3;
        o1.x = pref * p4; o1.y = pref * p5; o1.z = pref * p6; o1.w = pref * p7;
        float* __restrict__ dstp = orow + t * TILE + tid * VEC;
        *reinterpret_cast<vfloat4*>(dstp)     = o0;
        *reinterpret_cast<vfloat4*>(dstp + 4) = o1;

        carry *= btot;

        // Rotate the prefetch pipeline.
        a0 = a1; b0 = b1;
        a1 = an; b1 = bn;
    }
}

extern "C" void kernel_launch(void* const* d_in, const int* in_sizes, int n_in,
                              void* d_out, int out_size, void* d_ws, size_t ws_size,
                              hipStream_t stream) {
    const float* x = (const float*)d_in[0];
    float* out     = (float*)d_out;
    cumprod_w512_kernel<<<dim3(ROWS), dim3(BLOCK), 0, stream>>>(x, out);
}